// Round 4
// baseline (157.732 us; speedup 1.0000x reference)
//
#include <hip/hip_runtime.h>
#include <hip/hip_cooperative_groups.h>

namespace cg = cooperative_groups;

#define NN 1024
#define FF 7
#define HID 256
#define MLPH 64
#define OUTN 8
#define CATN (MLPH + HID + 8)   // 328

__device__ __forceinline__ float wave_sum(float v) {
#pragma unroll
    for (int m = 32; m >= 1; m >>= 1) v += __shfl_xor(v, m, 64);
    return v;
}
__device__ __forceinline__ float wave_max(float v) {
#pragma unroll
    for (int m = 32; m >= 1; m >>= 1) v = fmaxf(v, __shfl_xor(v, m, 64));
    return v;
}

// Single cooperative kernel: 256 WGs x 512 thr, 1 block/CU guaranteed resident.
// Block (b,jg), b=blk>>3, jg=blk&7.
// Phase 1: extract pts -> LDS (persists across grid sync), A-pass -> deg rows
//          jg*128..+128 + d2-max, MLP-L1 row h=jg*8+w per wave,
//          jg==0: speed sum + out zero, b in [8,16) & jg==7: E/cE collapse.
// grid.sync()  (deg complete, device-coherent)
// Phase 2: di = deg^-1/2 (full vector), B-pass slice, fused h/hsum partial,
//          project through E -> 8 floats, atomicAdd fan-in to out.
__global__ __launch_bounds__(512, 2) void gall(const float* __restrict__ x,
                                               const float* __restrict__ Wm0,
                                               const float* __restrict__ W2,
                                               const float* __restrict__ b2,
                                               const float* __restrict__ Wfc,
                                               const float* __restrict__ bfc,
                                               const float* __restrict__ W1,
                                               const float* __restrict__ b1,
                                               const float* __restrict__ Wg,
                                               const float* __restrict__ bg,
                                               const float* __restrict__ Wm1,
                                               const float* __restrict__ bm1,
                                               const float* __restrict__ Wp,
                                               const float* __restrict__ bp,
                                               const float* __restrict__ bm0,
                                               float* __restrict__ spd,
                                               float* __restrict__ mlp_p,
                                               float* __restrict__ E,
                                               float* __restrict__ cE,
                                               float* __restrict__ deg,
                                               float* __restrict__ bmaxp,
                                               float* __restrict__ out) {
    __shared__ __align__(16) float l0[NN];
    __shared__ __align__(16) float l1[NN];
    __shared__ __align__(16) float di[NN];
    __shared__ __align__(16) float s2[NN];
    __shared__ __align__(16) float r0[NN];
    __shared__ __align__(16) float r1[NN];
    __shared__ __align__(16) float r2[NN];
    __shared__ __align__(16) float q0s[128];
    __shared__ __align__(16) float q1s[128];
    __shared__ __align__(16) float qws[128];
    __shared__ __align__(16) float hp[512];
    __shared__ float sx1[MLPH], sxf2[MLPH], sglo[8];
    __shared__ float wred[8];
    __shared__ float eg0[HID], eg1[HID];

    int blk = blockIdx.x, tid = threadIdx.x, lane = tid & 63, w = tid >> 6;
    int b = blk >> 3, jg = blk & 7;
    const float* xb = x + b * (NN * FF);

    // ---- phase 1: pts extraction (l0/l1 persist through grid sync) ----
    {
        int j0 = tid, j1 = tid + 512;
        l0[j0] = xb[j0 * FF + 1]; l1[j0] = xb[j0 * FF + 2];
        l0[j1] = xb[j1 * FF + 1]; l1[j1] = xb[j1 * FF + 2];
    }
    __syncthreads();
    // ---- A-pass: lane = j-pair, wave = 128-wide k-slice ----
    int jA = jg * 128 + lane, jB = jA + 64;
    float pj0a = l0[jA], pj1a = l1[jA];
    float pj0b = l0[jB], pj1b = l1[jB];
    {
        const float4* v0p = (const float4*)&l0[w * 128];
        const float4* v1p = (const float4*)&l1[w * 128];
        unsigned dA = 0u, dB = 0u;
        float mx = 0.f;
#pragma unroll 4
        for (int g = 0; g < 32; ++g) {
            float4 v0 = v0p[g], v1 = v1p[g];
            float dx, dy, d2a, d2b;
            dx = pj0a - v0.x; dy = pj1a - v1.x; d2a = fmaf(dy, dy, dx * dx);
            dx = pj0b - v0.x; dy = pj1b - v1.x; d2b = fmaf(dy, dy, dx * dx);
            dA += (d2a <= 0.09f); dB += (d2b <= 0.09f);
            mx = fmaxf(mx, fmaxf(d2a, d2b));
            dx = pj0a - v0.y; dy = pj1a - v1.y; d2a = fmaf(dy, dy, dx * dx);
            dx = pj0b - v0.y; dy = pj1b - v1.y; d2b = fmaf(dy, dy, dx * dx);
            dA += (d2a <= 0.09f); dB += (d2b <= 0.09f);
            mx = fmaxf(mx, fmaxf(d2a, d2b));
            dx = pj0a - v0.z; dy = pj1a - v1.z; d2a = fmaf(dy, dy, dx * dx);
            dx = pj0b - v0.z; dy = pj1b - v1.z; d2b = fmaf(dy, dy, dx * dx);
            dA += (d2a <= 0.09f); dB += (d2b <= 0.09f);
            mx = fmaxf(mx, fmaxf(d2a, d2b));
            dx = pj0a - v0.w; dy = pj1a - v1.w; d2a = fmaf(dy, dy, dx * dx);
            dx = pj0b - v0.w; dy = pj1b - v1.w; d2b = fmaf(dy, dy, dx * dx);
            dA += (d2a <= 0.09f); dB += (d2b <= 0.09f);
            mx = fmaxf(mx, fmaxf(d2a, d2b));
        }
        s2[w * 128 + lane] = (float)dA;
        s2[w * 128 + 64 + lane] = (float)dB;
        mx = wave_max(mx);
        if (lane == 0) wred[w] = mx;
    }
    __syncthreads();
    if (tid < 128) {
        float s = 0.f;
#pragma unroll
        for (int kk = 0; kk < 8; ++kk) s += s2[kk * 128 + tid];
        deg[b * NN + jg * 128 + tid] = s;
    }
    if (tid == 0) {
        float m = wred[0];
#pragma unroll
        for (int i = 1; i < 8; ++i) m = fmaxf(m, wred[i]);
        bmaxp[b * 8 + jg] = m;
    }
    // ---- MLP-L1: wave w -> row h = jg*8+w ----
    {
        int h = jg * 8 + w;
        const float4* wr = (const float4*)(Wm0 + h * (NN * FF));
        const float4* xr = (const float4*)xb;
        float4 a4 = {0.f, 0.f, 0.f, 0.f};
#pragma unroll 7
        for (int it = 0; it < 28; ++it) {
            float4 wv = wr[it * 64 + lane];
            float4 xv = xr[it * 64 + lane];
            a4.x = fmaf(wv.x, xv.x, a4.x);
            a4.y = fmaf(wv.y, xv.y, a4.y);
            a4.z = fmaf(wv.z, xv.z, a4.z);
            a4.w = fmaf(wv.w, xv.w, a4.w);
        }
        float s = (a4.x + a4.y) + (a4.z + a4.w);
        s = wave_sum(s);
        if (lane == 0) mlp_p[b * MLPH + h] = s;
    }
    __syncthreads();   // bmax's wred consumed; safe to reuse
    if (jg == 0) {
        int j0 = tid, j1 = tid + 512;
        float vx = xb[j0 * FF + 3], vy = xb[j0 * FF + 4];
        float sp = sqrtf(fmaf(vx, vx, vy * vy));
        vx = xb[j1 * FF + 3]; vy = xb[j1 * FF + 4];
        sp += sqrtf(fmaf(vx, vx, vy * vy));
        sp = wave_sum(sp);
        if (lane == 0) wred[w] = sp;
        if (tid < OUTN) out[b * OUTN + tid] = 0.f;
    }
    __syncthreads();
    if (jg == 0 && tid == 0) {
        float s = 0.f;
#pragma unroll
        for (int i = 0; i < 8; ++i) s += wred[i];
        spd[b] = s;
    }
    if (b >= 8 && b < 16 && jg == 7) {   // E/cE collapse, 512-thread 2-way split
        int o = b - 8;
        int half = tid >> 8, col = tid & 255;
        if (tid < HID) eg0[tid] = Wp[o * CATN + MLPH + tid];
        __syncthreads();
        {
            float a = 0.f;
            const float* wcol = Wfc + (half * 128) * HID + col;
#pragma unroll 8
            for (int m = 0; m < 128; ++m) a = fmaf(eg0[half * 128 + m], wcol[m * HID], a);
            hp[tid] = a;
        }
        __syncthreads();
        if (tid < HID) eg1[tid] = hp[tid] + hp[tid + 256];
        __syncthreads();
        {
            float e = 0.f;
            const float* wcol = W2 + (half * 128) * HID + col;
#pragma unroll 8
            for (int k = 0; k < 128; ++k) e = fmaf(eg1[half * 128 + k], wcol[k * HID], e);
            hp[tid] = e;
        }
        __syncthreads();
        if (tid < HID) {
            E[o * HID + tid] = hp[tid] + hp[tid + 256];
            float c = fmaf(eg1[tid], b2[tid], eg0[tid] * bfc[tid]);
            c = wave_sum(c);
            if (lane == 0) wred[w] = c;
        }
        __syncthreads();
        if (tid == 0) cE[o] = wred[0] + wred[1] + wred[2] + wred[3];
    }

    // ======== grid-wide barrier: deg/spd/bmaxp/mlp_p/E/cE/out-zero ready =====
    cg::this_grid().sync();

    // ---- phase 2: B-pass (l0/l1 still resident in LDS) ----
    di[tid]       = 1.0f / sqrtf(deg[b * NN + tid]);
    di[tid + 512] = 1.0f / sqrtf(deg[b * NN + tid + 512]);
    __syncthreads();
    {
        const float4* v0p = (const float4*)&l0[w * 128];
        const float4* v1p = (const float4*)&l1[w * 128];
        const float4* vdp = (const float4*)&di[w * 128];
        float a0a = 0.f, a1a = 0.f, asa = 0.f;
        float a0b = 0.f, a1b = 0.f, asb = 0.f;
#pragma unroll 4
        for (int g = 0; g < 32; ++g) {
            float4 v0 = v0p[g], v1 = v1p[g], vd = vdp[g];
            float dx, dy, d2, t;
            dx = pj0a - v0.x; dy = pj1a - v1.x; d2 = fmaf(dy, dy, dx * dx);
            t = (d2 <= 0.09f) ? vd.x : 0.0f;
            a0a = fmaf(t, v0.x, a0a); a1a = fmaf(t, v1.x, a1a); asa += t;
            dx = pj0b - v0.x; dy = pj1b - v1.x; d2 = fmaf(dy, dy, dx * dx);
            t = (d2 <= 0.09f) ? vd.x : 0.0f;
            a0b = fmaf(t, v0.x, a0b); a1b = fmaf(t, v1.x, a1b); asb += t;
            dx = pj0a - v0.y; dy = pj1a - v1.y; d2 = fmaf(dy, dy, dx * dx);
            t = (d2 <= 0.09f) ? vd.y : 0.0f;
            a0a = fmaf(t, v0.y, a0a); a1a = fmaf(t, v1.y, a1a); asa += t;
            dx = pj0b - v0.y; dy = pj1b - v1.y; d2 = fmaf(dy, dy, dx * dx);
            t = (d2 <= 0.09f) ? vd.y : 0.0f;
            a0b = fmaf(t, v0.y, a0b); a1b = fmaf(t, v1.y, a1b); asb += t;
            dx = pj0a - v0.z; dy = pj1a - v1.z; d2 = fmaf(dy, dy, dx * dx);
            t = (d2 <= 0.09f) ? vd.z : 0.0f;
            a0a = fmaf(t, v0.z, a0a); a1a = fmaf(t, v1.z, a1a); asa += t;
            dx = pj0b - v0.z; dy = pj1b - v1.z; d2 = fmaf(dy, dy, dx * dx);
            t = (d2 <= 0.09f) ? vd.z : 0.0f;
            a0b = fmaf(t, v0.z, a0b); a1b = fmaf(t, v1.z, a1b); asb += t;
            dx = pj0a - v0.w; dy = pj1a - v1.w; d2 = fmaf(dy, dy, dx * dx);
            t = (d2 <= 0.09f) ? vd.w : 0.0f;
            a0a = fmaf(t, v0.w, a0a); a1a = fmaf(t, v1.w, a1a); asa += t;
            dx = pj0b - v0.w; dy = pj1b - v1.w; d2 = fmaf(dy, dy, dx * dx);
            t = (d2 <= 0.09f) ? vd.w : 0.0f;
            a0b = fmaf(t, v0.w, a0b); a1b = fmaf(t, v1.w, a1b); asb += t;
        }
        r0[w * 128 + lane] = a0a; r0[w * 128 + 64 + lane] = a0b;
        r1[w * 128 + lane] = a1a; r1[w * 128 + 64 + lane] = a1b;
        r2[w * 128 + lane] = asa; r2[w * 128 + 64 + lane] = asb;
    }
    __syncthreads();
    if (tid < 128) {
        float s0 = 0.f, s1 = 0.f, ss = 0.f;
#pragma unroll
        for (int kk = 0; kk < 8; ++kk) {
            s0 += r0[kk * 128 + tid];
            s1 += r1[kk * 128 + tid];
            ss += r2[kk * 128 + tid];
        }
        float dj = di[jg * 128 + tid];
        q0s[tid] = dj * s0;
        q1s[tid] = dj * s1;
        qws[tid] = dj * ss * (1.0f / NN);
    } else if (jg == 0 && tid < 192) {
        int t2 = tid - 128;
        sx1[t2] = fmaxf(mlp_p[b * MLPH + t2] + bm0[t2], 0.f);
    }
    __syncthreads();
    {   // fused h + weighted hsum partial over this block's 128 j
        int h = tid & 255, jq = tid >> 8;   // jq in {0,1}, 64 j each
        float w10 = W1[2 * h], w11 = W1[2 * h + 1], bb = b1[h];
        const float4* q0v = (const float4*)&q0s[jq * 64];
        const float4* q1v = (const float4*)&q1s[jq * 64];
        const float4* qwv = (const float4*)&qws[jq * 64];
        float acc = 0.f;
#pragma unroll
        for (int g = 0; g < 16; ++g) {
            float4 qa = q0v[g], qb = q1v[g], qw4 = qwv[g];
            acc = fmaf(qw4.x, fmaxf(fmaf(qb.x, w11, fmaf(qa.x, w10, bb)), 0.f), acc);
            acc = fmaf(qw4.y, fmaxf(fmaf(qb.y, w11, fmaf(qa.y, w10, bb)), 0.f), acc);
            acc = fmaf(qw4.z, fmaxf(fmaf(qb.z, w11, fmaf(qa.z, w10, bb)), 0.f), acc);
            acc = fmaf(qw4.w, fmaxf(fmaf(qb.w, w11, fmaf(qa.w, w10, bb)), 0.f), acc);
        }
        hp[jq * 256 + h] = acc;
    }
    __syncthreads();
    if (tid < HID) {
        r0[tid] = hp[tid] + hp[256 + tid];   // block's hs partial (r0 dead)
    } else if (jg == 0 && tid < HID + MLPH) {
        int t2 = tid - HID;
        float a = bm1[t2];
        const float* wv = Wm1 + t2 * MLPH;
#pragma unroll
        for (int k = 0; k < MLPH; ++k) a = fmaf(wv[k], sx1[k], a);
        sxf2[t2] = fmaxf(a, 0.f);
    } else if (jg == 0 && tid < HID + MLPH + 8) {
        int t2 = tid - HID - MLPH;
        float mxv = 0.f;
#pragma unroll
        for (int g = 0; g < 8; ++g) mxv = fmaxf(mxv, bmaxp[b * 8 + g]);
        float avg  = spd[b] * (1.0f / NN);
        float dens = 1.0f / sqrtf(mxv);
        sglo[t2] = fmaxf(fmaf(Wg[t2 * 2], avg, fmaf(Wg[t2 * 2 + 1], dens, bg[t2])), 0.f);
    }
    __syncthreads();
    // ---- project partial hs through E -> 8 floats, atomic fan-in ----
    {
        int o = w, ln = lane;   // 8 waves <-> 8 outputs
        const float* Eo = E + o * HID;
        float a = Eo[ln] * r0[ln];
        a = fmaf(Eo[ln + 64],  r0[ln + 64],  a);
        a = fmaf(Eo[ln + 128], r0[ln + 128], a);
        a = fmaf(Eo[ln + 192], r0[ln + 192], a);
        if (jg == 0) a = fmaf(Wp[o * CATN + ln], sxf2[ln], a);
        a = wave_sum(a);
        if (ln == 0) {
            if (jg == 0) {
                const float* wg = Wp + o * CATN + MLPH + HID;
#pragma unroll
                for (int g = 0; g < 8; ++g) a = fmaf(wg[g], sglo[g], a);
                a += cE[o] + bp[o];
            }
            atomicAdd(&out[b * OUTN + o], a);
        }
    }
}

extern "C" void kernel_launch(void* const* d_in, const int* in_sizes, int n_in,
                              void* d_out, int out_size, void* d_ws, size_t ws_size,
                              hipStream_t stream) {
    const float* x   = (const float*)d_in[0];
    const float* W1  = (const float*)d_in[1];
    const float* b1  = (const float*)d_in[2];
    const float* W2  = (const float*)d_in[3];
    const float* b2  = (const float*)d_in[4];
    const float* Wfc = (const float*)d_in[5];
    const float* bfc = (const float*)d_in[6];
    const float* Wg  = (const float*)d_in[7];
    const float* bg  = (const float*)d_in[8];
    const float* Wm0 = (const float*)d_in[9];
    const float* bm0 = (const float*)d_in[10];
    const float* Wm1 = (const float*)d_in[11];
    const float* bm1 = (const float*)d_in[12];
    const float* Wp  = (const float*)d_in[13];
    const float* bp  = (const float*)d_in[14];
    float* out = (float*)d_out;
    float* ws  = (float*)d_ws;

    float* deg   = ws;              // 32768
    float* mlp_p = ws + 32768;      // 2048
    float* bmaxp = ws + 34816;      // 256
    float* spd   = ws + 35072;      // 32
    float* E     = ws + 35104;      // 2048
    float* cE    = ws + 37152;      // 8
    // every ws cell is written before it is read each iteration -> no zero-init.

    void* kargs[] = {(void*)&x,   (void*)&Wm0, (void*)&W2,  (void*)&b2,
                     (void*)&Wfc, (void*)&bfc, (void*)&W1,  (void*)&b1,
                     (void*)&Wg,  (void*)&bg,  (void*)&Wm1, (void*)&bm1,
                     (void*)&Wp,  (void*)&bp,  (void*)&bm0,
                     (void*)&spd, (void*)&mlp_p, (void*)&E, (void*)&cE,
                     (void*)&deg, (void*)&bmaxp, (void*)&out};
    hipLaunchCooperativeKernel(reinterpret_cast<void*>(gall), dim3(256), dim3(512),
                               kargs, 0, stream);
}

// Round 5
// 113.350 us; speedup vs baseline: 1.3916x; 1.3916x over previous
//
#include <hip/hip_runtime.h>

#define NN 1024
#define FF 7
#define HID 256
#define MLPH 64
#define OUTN 8
#define CATN (MLPH + HID + 8)   // 328

__device__ __forceinline__ float wave_sum(float v) {
#pragma unroll
    for (int m = 32; m >= 1; m >>= 1) v += __shfl_xor(v, m, 64);
    return v;
}
__device__ __forceinline__ float wave_max(float v) {
#pragma unroll
    for (int m = 32; m >= 1; m >>= 1) v = fmaxf(v, __shfl_xor(v, m, 64));
    return v;
}

// g1: 256 WGs x 512 thr. Block (b,jg).
// ALL cold global loads are issued in one burst at kernel entry (Wm0 row ->
// 28 float4 regs per thread, x[b] -> LDS via reg roundtrip). The single vmcnt
// drain before __syncthreads pays HBM latency ONCE for ~32 in-flight loads
// per thread instead of per-batch. A-pass + MLP-L1 then run from LDS/regs.
// jg==0: speed sum (from LDS) + out zero. b in [8,16) & jg==7: E/cE collapse.
__global__ __launch_bounds__(512, 2) void g1(const float* __restrict__ x,
                                             const float* __restrict__ Wm0,
                                             const float* __restrict__ W2,
                                             const float* __restrict__ b2,
                                             const float* __restrict__ Wfc,
                                             const float* __restrict__ bfc,
                                             const float* __restrict__ Wp,
                                             float* __restrict__ spd,
                                             float* __restrict__ mlp_p,
                                             float* __restrict__ E,
                                             float* __restrict__ cE,
                                             float* __restrict__ deg,
                                             float* __restrict__ bmaxp,
                                             float* __restrict__ out) {
    __shared__ __align__(16) float lxs[NN * FF];   // full x[b], 28 KB
    __shared__ __align__(16) float l0[NN];
    __shared__ __align__(16) float l1[NN];
    __shared__ __align__(16) float s2[NN];         // deg partials; reused as E's hp
    __shared__ float wred[8];
    __shared__ float eg0[HID];
    __shared__ float eg1[HID];
    int blk = blockIdx.x, tid = threadIdx.x, lane = tid & 63, w = tid >> 6;
    int b = blk >> 3, jg = blk & 7;

    // ---- cold-load burst: everything issued before any wait ----
    const float4* wr = (const float4*)(Wm0 + (jg * 8 + w) * (NN * FF));
    float4 wreg[28];
#pragma unroll
    for (int t = 0; t < 28; ++t) wreg[t] = wr[t * 64 + lane];
    const float4* xr4 = (const float4*)(x + b * (NN * FF));
    float4 xreg0 = xr4[tid];
    float4 xreg1 = xr4[512 + tid];
    float4 xreg2 = xr4[1024 + tid];
    float4 xreg3;
    if (tid < 256) xreg3 = xr4[1536 + tid];
    float4* lx4 = (float4*)lxs;
    lx4[tid] = xreg0;                  // first wait here drains ALL loads above
    lx4[512 + tid] = xreg1;
    lx4[1024 + tid] = xreg2;
    if (tid < 256) lx4[1536 + tid] = xreg3;
    __syncthreads();
    // ---- extract pts (stride-7 LDS reads: 2-way bank alias, free) ----
    l0[tid] = lxs[tid * 7 + 1];       l1[tid] = lxs[tid * 7 + 2];
    l0[tid + 512] = lxs[(tid + 512) * 7 + 1];
    l1[tid + 512] = lxs[(tid + 512) * 7 + 2];
    __syncthreads();
    // ---- A-pass: lane = j-pair, wave = 128-wide k-slice ----
    int jA = jg * 128 + lane, jB = jA + 64;
    float pj0a = l0[jA], pj1a = l1[jA];
    float pj0b = l0[jB], pj1b = l1[jB];
    {
        const float4* v0p = (const float4*)&l0[w * 128];
        const float4* v1p = (const float4*)&l1[w * 128];
        unsigned dA = 0u, dB = 0u;
        float mx = 0.f;
#pragma unroll 4
        for (int g = 0; g < 32; ++g) {
            float4 v0 = v0p[g], v1 = v1p[g];
            float dx, dy, d2a, d2b;
            dx = pj0a - v0.x; dy = pj1a - v1.x; d2a = fmaf(dy, dy, dx * dx);
            dx = pj0b - v0.x; dy = pj1b - v1.x; d2b = fmaf(dy, dy, dx * dx);
            dA += (d2a <= 0.09f); dB += (d2b <= 0.09f);
            mx = fmaxf(mx, fmaxf(d2a, d2b));
            dx = pj0a - v0.y; dy = pj1a - v1.y; d2a = fmaf(dy, dy, dx * dx);
            dx = pj0b - v0.y; dy = pj1b - v1.y; d2b = fmaf(dy, dy, dx * dx);
            dA += (d2a <= 0.09f); dB += (d2b <= 0.09f);
            mx = fmaxf(mx, fmaxf(d2a, d2b));
            dx = pj0a - v0.z; dy = pj1a - v1.z; d2a = fmaf(dy, dy, dx * dx);
            dx = pj0b - v0.z; dy = pj1b - v1.z; d2b = fmaf(dy, dy, dx * dx);
            dA += (d2a <= 0.09f); dB += (d2b <= 0.09f);
            mx = fmaxf(mx, fmaxf(d2a, d2b));
            dx = pj0a - v0.w; dy = pj1a - v1.w; d2a = fmaf(dy, dy, dx * dx);
            dx = pj0b - v0.w; dy = pj1b - v1.w; d2b = fmaf(dy, dy, dx * dx);
            dA += (d2a <= 0.09f); dB += (d2b <= 0.09f);
            mx = fmaxf(mx, fmaxf(d2a, d2b));
        }
        s2[w * 128 + lane] = (float)dA;
        s2[w * 128 + 64 + lane] = (float)dB;
        mx = wave_max(mx);
        if (lane == 0) wred[w] = mx;
    }
    __syncthreads();
    if (tid < 128) {
        float s = 0.f;
#pragma unroll
        for (int kk = 0; kk < 8; ++kk) s += s2[kk * 128 + tid];
        deg[b * NN + jg * 128 + tid] = s;
    }
    if (tid == 0) {
        float m = wred[0];
#pragma unroll
        for (int i = 1; i < 8; ++i) m = fmaxf(m, wred[i]);
        bmaxp[b * 8 + jg] = m;
    }
    // ---- MLP-L1: consume wreg (registers) x lxs (LDS), zero global reads ----
    {
        float4 a4 = {0.f, 0.f, 0.f, 0.f};
#pragma unroll
        for (int t = 0; t < 28; ++t) {
            float4 xv = lx4[t * 64 + lane];
            a4.x = fmaf(wreg[t].x, xv.x, a4.x);
            a4.y = fmaf(wreg[t].y, xv.y, a4.y);
            a4.z = fmaf(wreg[t].z, xv.z, a4.z);
            a4.w = fmaf(wreg[t].w, xv.w, a4.w);
        }
        float s = (a4.x + a4.y) + (a4.z + a4.w);
        s = wave_sum(s);
        if (lane == 0) mlp_p[b * MLPH + jg * 8 + w] = s;
    }
    __syncthreads();   // bmax's wred consumed; safe to reuse
    if (jg == 0) {
        float vx = lxs[tid * 7 + 3], vy = lxs[tid * 7 + 4];
        float sp = sqrtf(fmaf(vx, vx, vy * vy));
        vx = lxs[(tid + 512) * 7 + 3]; vy = lxs[(tid + 512) * 7 + 4];
        sp += sqrtf(fmaf(vx, vx, vy * vy));
        sp = wave_sum(sp);
        if (lane == 0) wred[w] = sp;
        if (tid < OUTN) out[b * OUTN + tid] = 0.f;
    }
    __syncthreads();
    if (jg == 0 && tid == 0) {
        float s = 0.f;
#pragma unroll
        for (int i = 0; i < 8; ++i) s += wred[i];
        spd[b] = s;
    }
    if (b >= 8 && b < 16 && jg == 7) {   // E/cE collapse, 2-way split; hp := s2
        int o = b - 8;
        int half = tid >> 8, col = tid & 255;
        float* hp = s2;
        if (tid < HID) eg0[tid] = Wp[o * CATN + MLPH + tid];
        __syncthreads();
        {
            float a = 0.f;
            const float* wcol = Wfc + (half * 128) * HID + col;
#pragma unroll 8
            for (int m = 0; m < 128; ++m) a = fmaf(eg0[half * 128 + m], wcol[m * HID], a);
            hp[tid] = a;
        }
        __syncthreads();
        if (tid < HID) eg1[tid] = hp[tid] + hp[tid + 256];
        __syncthreads();
        {
            float e = 0.f;
            const float* wcol = W2 + (half * 128) * HID + col;
#pragma unroll 8
            for (int k = 0; k < 128; ++k) e = fmaf(eg1[half * 128 + k], wcol[k * HID], e);
            hp[tid] = e;
        }
        __syncthreads();
        if (tid < HID) {
            E[o * HID + tid] = hp[tid] + hp[tid + 256];
            float c = fmaf(eg1[tid], b2[tid], eg0[tid] * bfc[tid]);
            c = wave_sum(c);
            if (lane == 0) wred[w] = c;
        }
        __syncthreads();
        if (tid == 0) cE[o] = wred[0] + wred[1] + wred[2] + wred[3];
    }
}

// g2: 256 WGs x 512 thr. B-pass slice + fused h/hsum partial + E-projection
// + atomicAdd fan-in to out (proven in rounds 2/3). jg==0 folds MLP-L2,
// global branch, cE, bp.
__global__ __launch_bounds__(512, 4) void g2(const float* __restrict__ x,
                                             const float* __restrict__ deg,
                                             const float* __restrict__ W1,
                                             const float* __restrict__ b1,
                                             const float* __restrict__ Wg,
                                             const float* __restrict__ bg,
                                             const float* __restrict__ Wm1,
                                             const float* __restrict__ bm1,
                                             const float* __restrict__ Wp,
                                             const float* __restrict__ bp,
                                             const float* __restrict__ bm0,
                                             const float* __restrict__ mlp_p,
                                             const float* __restrict__ bmaxp,
                                             const float* __restrict__ spd,
                                             const float* __restrict__ E,
                                             const float* __restrict__ cE,
                                             float* __restrict__ out) {
    __shared__ __align__(16) float l0[NN];
    __shared__ __align__(16) float l1[NN];
    __shared__ __align__(16) float di[NN];
    __shared__ __align__(16) float r0[8 * 128];
    __shared__ __align__(16) float r1[8 * 128];
    __shared__ __align__(16) float r2[8 * 128];
    __shared__ __align__(16) float q0s[128];
    __shared__ __align__(16) float q1s[128];
    __shared__ __align__(16) float qws[128];
    __shared__ __align__(16) float hp[512];
    __shared__ float sx1[MLPH], sxf2[MLPH], sglo[8];
    int blk = blockIdx.x, tid = threadIdx.x, lane = tid & 63, w = tid >> 6;
    int b = blk >> 3, jg = blk & 7;
    const float* xb = x + b * (NN * FF);
    {
        int j0 = tid, j1 = tid + 512;
        l0[j0] = xb[j0 * FF + 1]; l1[j0] = xb[j0 * FF + 2];
        l0[j1] = xb[j1 * FF + 1]; l1[j1] = xb[j1 * FF + 2];
        di[j0] = 1.0f / sqrtf(deg[b * NN + j0]);
        di[j1] = 1.0f / sqrtf(deg[b * NN + j1]);
    }
    __syncthreads();
    int jA = jg * 128 + lane, jB = jA + 64;
    float pj0a = l0[jA], pj1a = l1[jA];
    float pj0b = l0[jB], pj1b = l1[jB];
    const float4* v0p = (const float4*)&l0[w * 128];
    const float4* v1p = (const float4*)&l1[w * 128];
    const float4* vdp = (const float4*)&di[w * 128];
    float a0a = 0.f, a1a = 0.f, asa = 0.f;
    float a0b = 0.f, a1b = 0.f, asb = 0.f;
#pragma unroll 4
    for (int g = 0; g < 32; ++g) {
        float4 v0 = v0p[g], v1 = v1p[g], vd = vdp[g];
        float dx, dy, d2, t;
        dx = pj0a - v0.x; dy = pj1a - v1.x; d2 = fmaf(dy, dy, dx * dx);
        t = (d2 <= 0.09f) ? vd.x : 0.0f;
        a0a = fmaf(t, v0.x, a0a); a1a = fmaf(t, v1.x, a1a); asa += t;
        dx = pj0b - v0.x; dy = pj1b - v1.x; d2 = fmaf(dy, dy, dx * dx);
        t = (d2 <= 0.09f) ? vd.x : 0.0f;
        a0b = fmaf(t, v0.x, a0b); a1b = fmaf(t, v1.x, a1b); asb += t;
        dx = pj0a - v0.y; dy = pj1a - v1.y; d2 = fmaf(dy, dy, dx * dx);
        t = (d2 <= 0.09f) ? vd.y : 0.0f;
        a0a = fmaf(t, v0.y, a0a); a1a = fmaf(t, v1.y, a1a); asa += t;
        dx = pj0b - v0.y; dy = pj1b - v1.y; d2 = fmaf(dy, dy, dx * dx);
        t = (d2 <= 0.09f) ? vd.y : 0.0f;
        a0b = fmaf(t, v0.y, a0b); a1b = fmaf(t, v1.y, a1b); asb += t;
        dx = pj0a - v0.z; dy = pj1a - v1.z; d2 = fmaf(dy, dy, dx * dx);
        t = (d2 <= 0.09f) ? vd.z : 0.0f;
        a0a = fmaf(t, v0.z, a0a); a1a = fmaf(t, v1.z, a1a); asa += t;
        dx = pj0b - v0.z; dy = pj1b - v1.z; d2 = fmaf(dy, dy, dx * dx);
        t = (d2 <= 0.09f) ? vd.z : 0.0f;
        a0b = fmaf(t, v0.z, a0b); a1b = fmaf(t, v1.z, a1b); asb += t;
        dx = pj0a - v0.w; dy = pj1a - v1.w; d2 = fmaf(dy, dy, dx * dx);
        t = (d2 <= 0.09f) ? vd.w : 0.0f;
        a0a = fmaf(t, v0.w, a0a); a1a = fmaf(t, v1.w, a1a); asa += t;
        dx = pj0b - v0.w; dy = pj1b - v1.w; d2 = fmaf(dy, dy, dx * dx);
        t = (d2 <= 0.09f) ? vd.w : 0.0f;
        a0b = fmaf(t, v0.w, a0b); a1b = fmaf(t, v1.w, a1b); asb += t;
    }
    r0[w * 128 + lane] = a0a; r0[w * 128 + 64 + lane] = a0b;
    r1[w * 128 + lane] = a1a; r1[w * 128 + 64 + lane] = a1b;
    r2[w * 128 + lane] = asa; r2[w * 128 + 64 + lane] = asb;
    __syncthreads();
    if (tid < 128) {
        float s0 = 0.f, s1 = 0.f, ss = 0.f;
#pragma unroll
        for (int kk = 0; kk < 8; ++kk) {
            s0 += r0[kk * 128 + tid];
            s1 += r1[kk * 128 + tid];
            ss += r2[kk * 128 + tid];
        }
        float dj = di[jg * 128 + tid];
        q0s[tid] = dj * s0;
        q1s[tid] = dj * s1;
        qws[tid] = dj * ss * (1.0f / NN);
    } else if (jg == 0 && tid < 192) {
        int t2 = tid - 128;
        sx1[t2] = fmaxf(mlp_p[b * MLPH + t2] + bm0[t2], 0.f);
    }
    __syncthreads();
    {   // fused h + weighted hsum partial over this block's 128 j
        int h = tid & 255, jq = tid >> 8;   // jq in {0,1}, 64 j each
        float w10 = W1[2 * h], w11 = W1[2 * h + 1], bb = b1[h];
        const float4* q0v = (const float4*)&q0s[jq * 64];
        const float4* q1v = (const float4*)&q1s[jq * 64];
        const float4* qwv = (const float4*)&qws[jq * 64];
        float acc = 0.f;
#pragma unroll
        for (int g = 0; g < 16; ++g) {
            float4 qa = q0v[g], qb = q1v[g], qw4 = qwv[g];
            acc = fmaf(qw4.x, fmaxf(fmaf(qb.x, w11, fmaf(qa.x, w10, bb)), 0.f), acc);
            acc = fmaf(qw4.y, fmaxf(fmaf(qb.y, w11, fmaf(qa.y, w10, bb)), 0.f), acc);
            acc = fmaf(qw4.z, fmaxf(fmaf(qb.z, w11, fmaf(qa.z, w10, bb)), 0.f), acc);
            acc = fmaf(qw4.w, fmaxf(fmaf(qb.w, w11, fmaf(qa.w, w10, bb)), 0.f), acc);
        }
        hp[jq * 256 + h] = acc;
    }
    __syncthreads();
    if (tid < HID) {
        r0[tid] = hp[tid] + hp[256 + tid];   // block's hs partial (r0 dead)
    } else if (jg == 0 && tid < HID + MLPH) {
        int t2 = tid - HID;
        float a = bm1[t2];
        const float* wv = Wm1 + t2 * MLPH;
#pragma unroll
        for (int k = 0; k < MLPH; ++k) a = fmaf(wv[k], sx1[k], a);
        sxf2[t2] = fmaxf(a, 0.f);
    } else if (jg == 0 && tid < HID + MLPH + 8) {
        int t2 = tid - HID - MLPH;
        float mxv = 0.f;
#pragma unroll
        for (int g = 0; g < 8; ++g) mxv = fmaxf(mxv, bmaxp[b * 8 + g]);
        float avg  = spd[b] * (1.0f / NN);
        float dens = 1.0f / sqrtf(mxv);
        sglo[t2] = fmaxf(fmaf(Wg[t2 * 2], avg, fmaf(Wg[t2 * 2 + 1], dens, bg[t2])), 0.f);
    }
    __syncthreads();
    // ---- project partial hs through E -> 8 floats, atomic fan-in ----
    {
        int o = w, ln = lane;   // 8 waves <-> 8 outputs
        const float* Eo = E + o * HID;
        float a = Eo[ln] * r0[ln];
        a = fmaf(Eo[ln + 64],  r0[ln + 64],  a);
        a = fmaf(Eo[ln + 128], r0[ln + 128], a);
        a = fmaf(Eo[ln + 192], r0[ln + 192], a);
        if (jg == 0) a = fmaf(Wp[o * CATN + ln], sxf2[ln], a);
        a = wave_sum(a);
        if (ln == 0) {
            if (jg == 0) {
                const float* wg = Wp + o * CATN + MLPH + HID;
#pragma unroll
                for (int g = 0; g < 8; ++g) a = fmaf(wg[g], sglo[g], a);
                a += cE[o] + bp[o];
            }
            atomicAdd(&out[b * OUTN + o], a);
        }
    }
}

extern "C" void kernel_launch(void* const* d_in, const int* in_sizes, int n_in,
                              void* d_out, int out_size, void* d_ws, size_t ws_size,
                              hipStream_t stream) {
    const float* x   = (const float*)d_in[0];
    const float* W1  = (const float*)d_in[1];
    const float* b1  = (const float*)d_in[2];
    const float* W2  = (const float*)d_in[3];
    const float* b2  = (const float*)d_in[4];
    const float* Wfc = (const float*)d_in[5];
    const float* bfc = (const float*)d_in[6];
    const float* Wg  = (const float*)d_in[7];
    const float* bg  = (const float*)d_in[8];
    const float* Wm0 = (const float*)d_in[9];
    const float* bm0 = (const float*)d_in[10];
    const float* Wm1 = (const float*)d_in[11];
    const float* bm1 = (const float*)d_in[12];
    const float* Wp  = (const float*)d_in[13];
    const float* bp  = (const float*)d_in[14];
    float* out = (float*)d_out;
    float* ws  = (float*)d_ws;

    float* deg   = ws;              // 32768
    float* mlp_p = ws + 32768;      // 2048
    float* bmaxp = ws + 34816;      // 256
    float* spd   = ws + 35072;      // 32
    float* E     = ws + 35104;      // 2048
    float* cE    = ws + 37152;      // 8
    // every ws cell is written before it is read each iteration -> no zero-init.

    g1<<<256, 512, 0, stream>>>(x, Wm0, W2, b2, Wfc, bfc, Wp,
                                spd, mlp_p, E, cE, deg, bmaxp, out);
    g2<<<256, 512, 0, stream>>>(x, deg, W1, b1, Wg, bg, Wm1, bm1,
                                Wp, bp, bm0, mlp_p, bmaxp, spd, E, cE, out);
}